// Round 9
// baseline (492.315 us; speedup 1.0000x reference)
//
#include <hip/hip_runtime.h>
#include <hip/hip_cooperative_groups.h>

namespace cg = cooperative_groups;

// GCN link predictor. fp32 math, bf16 intermediates + bf16 MFMA GEMM.
// Pipeline: coop CSR build (hist -> bucket scans -> stage -> scatter[+row_ptr,dinv], ONE
//           cooperative kernel w/ grid.sync) -> [MFMA GEMM+dinv-scale -> gather-agg]x2 -> decode.
// norm factorization: h'[i] = dinv[i]*(x@W)[i];  z[i] = dinv[i]*(h'[i] + sum_{src->i} h'[src]) + b.
// R3: gathers half-wave float4. R4: bf16 intermediates. R5: MFMA GEMM. R6 FAILED: hot global
// atomics. R7: deterministic-offset bucket CSR. R8: decode 4-pairs/half-wave + agg unroll-8.
// R9: CSR 5 kernels -> 1 cooperative kernel (12 -> 6 dispatches; launch-gap hypothesis test).

typedef __attribute__((ext_vector_type(8))) short short8;   // 8 bf16 (A/B frag)
typedef __attribute__((ext_vector_type(4))) float floatx4;  // C/D frag

#define CSR_G 512   // coop grid; phase-B scan hardcodes 2 values/thread (512 = 2*256)

__device__ __forceinline__ unsigned short f2bf(float f) {
    union { float f; unsigned int u; } v; v.f = f;
    unsigned int u = v.u;
    u += 0x7fffu + ((u >> 16) & 1u);   // round-to-nearest-even
    return (unsigned short)(u >> 16);
}

__device__ __forceinline__ unsigned int pack2(float a, float b) {
    return (unsigned int)f2bf(a) | ((unsigned int)f2bf(b) << 16);
}

__device__ __forceinline__ float4 cvt4(uint2 u) {
    float4 f;
    f.x = __uint_as_float(u.x << 16);
    f.y = __uint_as_float(u.x & 0xffff0000u);
    f.z = __uint_as_float(u.y << 16);
    f.w = __uint_as_float(u.y & 0xffff0000u);
    return f;
}

// --- CSR build: single cooperative kernel ---
// Phases: A hist (LDS) -> B per-bucket scan over G blocks -> C bucket-base scan ->
//         D stage (deterministic offsets, LDS cursors) -> E per-bucket scatter + row_ptr/dinv.
__global__ __launch_bounds__(256) void csr_coop_kernel(const int* __restrict__ src,
                                                       const int* __restrict__ dst,
                                                       int* __restrict__ bhist,
                                                       int* __restrict__ T,
                                                       int* __restrict__ bucket_base,
                                                       unsigned int* __restrict__ stage,
                                                       int* __restrict__ row_ptr,
                                                       float* __restrict__ dinv,
                                                       int* __restrict__ srcs_sorted,
                                                       int E, int N, int NB) {
    cg::grid_group grid = cg::this_grid();
    __shared__ int sh[1024];
    const int t = threadIdx.x, g = blockIdx.x;
    const int G = CSR_G;
    const int chunk = (E + G - 1) / G;
    const int elo = g * chunk, ehi = min(elo + chunk, E);

    // Phase A: per-block bucket histogram (LDS atomics only)
    for (int b = t; b < NB; b += 256) sh[b] = 0;
    __syncthreads();
    for (int i = elo + t; i < ehi; i += 256) atomicAdd(&sh[dst[i] >> 6], 1);
    __syncthreads();
    for (int b = t; b < NB; b += 256) bhist[(size_t)g * NB + b] = sh[b];

    grid.sync();

    // Phase B: per-bucket exclusive scan over the G block-counts (2 values/thread)
    for (int b = g; b < NB; b += G) {
        int v0 = bhist[(size_t)(2 * t) * NB + b];
        int v1 = bhist[(size_t)(2 * t + 1) * NB + b];
        int s = v0 + v1;
        int cur = 0;
        sh[t] = s;
        __syncthreads();
#pragma unroll
        for (int off = 1; off < 256; off <<= 1) {
            int val = sh[cur * 256 + t];
            if (t >= off) val += sh[cur * 256 + t - off];
            sh[(1 - cur) * 256 + t] = val;
            __syncthreads();
            cur = 1 - cur;
        }
        int inc = sh[cur * 256 + t];
        int exc = inc - s;
        bhist[(size_t)(2 * t) * NB + b] = exc;
        bhist[(size_t)(2 * t + 1) * NB + b] = exc + v0;
        if (t == 255) T[b] = inc;
        __syncthreads();
    }

    grid.sync();

    // Phase C: exclusive scan of bucket totals -> bucket_base (block 0 only)
    if (g == 0) {
        int cb = (NB + 255) >> 8;
        int lo = t * cb, hi = min(lo + cb, NB);
        int s = 0;
        for (int i = lo; i < hi; ++i) s += T[i];
        sh[t] = s;
        __syncthreads();
        if (t == 0) {
            int run = 0;
            for (int i = 0; i < 256; ++i) { int v = sh[i]; sh[i] = run; run += v; }
        }
        __syncthreads();
        int run = sh[t];
        for (int i = lo; i < hi; ++i) { bucket_base[i] = run; run += T[i]; }
        if (lo < NB && hi == NB) bucket_base[NB] = run;   // == E
    }

    grid.sync();

    // Phase D: stage packed records at deterministic per-(block,bucket) offsets
    for (int b = t; b < NB; b += 256) sh[b] = bucket_base[b] + bhist[(size_t)g * NB + b];
    __syncthreads();
    for (int i = elo + t; i < ehi; i += 256) {
        int d = dst[i];
        int pos = atomicAdd(&sh[d >> 6], 1);
        stage[pos] = ((unsigned int)src[i] << 6) | (unsigned int)(d & 63);
    }

    grid.sync();

    // Phase E: per-bucket scatter; emits row_ptr + dinv. sh[0..63]=cnt, sh[64..127]=lcur.
    for (int b = g; b < NB; b += G) {
        int lob = b << 6;
        int base = bucket_base[b], basen = bucket_base[b + 1];
        if (t < 64) sh[t] = 0;
        __syncthreads();
        for (int i = base + t; i < basen; i += 256) atomicAdd(&sh[stage[i] & 63u], 1);
        __syncthreads();
        if (t < 64) {
            int v = sh[t];
            int inc = v;
#pragma unroll
            for (int off = 1; off < 64; off <<= 1) {
                int x = __shfl_up(inc, off, 64);
                if (t >= off) inc += x;
            }
            int exc = inc - v;
            int node = lob + t;
            if (node < N) {
                row_ptr[node] = base + exc;
                dinv[node] = rsqrtf((float)(v + 1));   // +1 self-loop
                if (node == N - 1) row_ptr[N] = base + exc + v;
            }
            sh[64 + t] = base + exc;
        }
        __syncthreads();
        for (int i = base + t; i < basen; i += 256) {
            unsigned int rec = stage[i];
            int pos = atomicAdd(&sh[64 + (rec & 63u)], 1);
            srcs_sorted[pos] = (int)(rec >> 6);
        }
        __syncthreads();
    }
}

// --- MFMA GEMM: H[r][c] = bf16( dinv[r] * sum_k X[r][k]*W[k][c] ), 64x128 per block ---
template <bool BF16IN>
__global__ __launch_bounds__(256) void gemm_mfma_kernel(const void* __restrict__ Xv,
                                                        const float* __restrict__ W,
                                                        const float* __restrict__ dinv,
                                                        uint2* __restrict__ H, int N) {
    __shared__ __align__(16) char smem[50176];
    short* WB = (short*)smem;            // [nt][kt][lane][j]
    short* XL = (short*)(smem + 32768);  // [row][k], row stride 136 shorts
    float* Cst = (float*)smem;           // epilogue overlap: [row][col], stride 132 floats

    const int tid = threadIdx.x;
    const int w = tid >> 6;
    const int lane = tid & 63;
    const int blk = blockIdx.x;

    {
        const float4* W4 = (const float4*)W;
#pragma unroll
        for (int i = 0; i < 16; ++i) {
            int f = tid + i * 256;
            int k = f >> 5;
            int c4 = f & 31;
            float4 wv = W4[f];
            int kt = k >> 5, q = (k >> 3) & 3, j = k & 7;
            float e[4] = {wv.x, wv.y, wv.z, wv.w};
#pragma unroll
            for (int m = 0; m < 4; ++m) {
                int c = c4 * 4 + m;
                int nt = c >> 4;
                int ln = q * 16 + (c & 15);
                WB[((nt * 4 + kt) * 64 + ln) * 8 + j] = (short)f2bf(e[m]);
            }
        }
    }
    {
#pragma unroll
        for (int i = 0; i < 8; ++i) {
            int f = tid + i * 256;
            int row = f >> 5;
            int c4 = f & 31;
            int gr = min(blk * 64 + row, N - 1);
            uint2 u;
            if constexpr (BF16IN) {
                u = ((const uint2*)Xv)[(size_t)gr * 32 + c4];
            } else {
                float4 xv = ((const float4*)Xv)[(size_t)gr * 32 + c4];
                u.x = pack2(xv.x, xv.y);
                u.y = pack2(xv.z, xv.w);
            }
            *(uint2*)&XL[row * 136 + c4 * 4] = u;
        }
    }
    __syncthreads();

    const int arow = w * 16 + (lane & 15);
    const int koff = (lane >> 4) * 8;
    short8 a[4];
#pragma unroll
    for (int kt = 0; kt < 4; ++kt)
        a[kt] = *(const short8*)&XL[arow * 136 + kt * 32 + koff];

    floatx4 acc[8];
#pragma unroll
    for (int nt = 0; nt < 8; ++nt) acc[nt] = (floatx4){0.f, 0.f, 0.f, 0.f};

#pragma unroll
    for (int kt = 0; kt < 4; ++kt) {
#pragma unroll
        for (int nt = 0; nt < 8; ++nt) {
            short8 b = *(const short8*)&WB[((nt * 4 + kt) * 64 + lane) * 8];
            acc[nt] = __builtin_amdgcn_mfma_f32_16x16x32_bf16(a[kt], b, acc[nt], 0, 0, 0);
        }
    }
    __syncthreads();

    {
        int q = lane >> 4, cn = lane & 15;
#pragma unroll
        for (int nt = 0; nt < 8; ++nt)
#pragma unroll
            for (int r = 0; r < 4; ++r)
                Cst[(w * 16 + q * 4 + r) * 132 + nt * 16 + cn] = acc[nt][r];
    }
    __syncthreads();
    {
#pragma unroll
        for (int i = 0; i < 8; ++i) {
            int f = tid + i * 256;
            int row = f >> 5;
            int c4 = f & 31;
            int gr = blk * 64 + row;
            if (gr < N) {
                float4 v = *(float4*)&Cst[row * 132 + c4 * 4];
                float di = dinv[gr];
                uint2 o;
                o.x = pack2(v.x * di, v.y * di);
                o.y = pack2(v.z * di, v.w * di);
                H[(size_t)gr * 32 + c4] = o;
            }
        }
    }
}

// Half-wave (32 lanes) per node; lane holds 4 cols as bf16x4 (uint2). fp32 accumulate.
// Edge loop: unroll-8 (4 accs) -> unroll-4 -> scalar tail.
__global__ __launch_bounds__(256) void agg_kernel(const unsigned short* __restrict__ Hp,
                                                  const int* __restrict__ row_ptr,
                                                  const int* __restrict__ srcs,
                                                  const float* __restrict__ dinv,
                                                  const float* __restrict__ bias,
                                                  unsigned short* __restrict__ Z,
                                                  int N, int do_relu) {
    int gw = (int)((blockIdx.x * blockDim.x + threadIdx.x) >> 6);
    int lane = threadIdx.x & 63;
    int half = lane >> 5;
    int hl = lane & 31;
    int n = gw * 2 + half;
    if (n >= N) return;

    const uint2* H2 = (const uint2*)Hp;
    float4 a0 = cvt4(H2[(size_t)n * 32 + hl]);  // self-loop term
    float4 a1 = make_float4(0.f, 0.f, 0.f, 0.f);
    float4 a2 = make_float4(0.f, 0.f, 0.f, 0.f);
    float4 a3 = make_float4(0.f, 0.f, 0.f, 0.f);

    int j = row_ptr[n], end = row_ptr[n + 1];
    for (; j + 7 < end; j += 8) {
        uint2 u0 = H2[(size_t)srcs[j + 0] * 32 + hl];
        uint2 u1 = H2[(size_t)srcs[j + 1] * 32 + hl];
        uint2 u2 = H2[(size_t)srcs[j + 2] * 32 + hl];
        uint2 u3 = H2[(size_t)srcs[j + 3] * 32 + hl];
        uint2 u4 = H2[(size_t)srcs[j + 4] * 32 + hl];
        uint2 u5 = H2[(size_t)srcs[j + 5] * 32 + hl];
        uint2 u6 = H2[(size_t)srcs[j + 6] * 32 + hl];
        uint2 u7 = H2[(size_t)srcs[j + 7] * 32 + hl];
        float4 t;
        t = cvt4(u0); a0.x += t.x; a0.y += t.y; a0.z += t.z; a0.w += t.w;
        t = cvt4(u1); a1.x += t.x; a1.y += t.y; a1.z += t.z; a1.w += t.w;
        t = cvt4(u2); a2.x += t.x; a2.y += t.y; a2.z += t.z; a2.w += t.w;
        t = cvt4(u3); a3.x += t.x; a3.y += t.y; a3.z += t.z; a3.w += t.w;
        t = cvt4(u4); a0.x += t.x; a0.y += t.y; a0.z += t.z; a0.w += t.w;
        t = cvt4(u5); a1.x += t.x; a1.y += t.y; a1.z += t.z; a1.w += t.w;
        t = cvt4(u6); a2.x += t.x; a2.y += t.y; a2.z += t.z; a2.w += t.w;
        t = cvt4(u7); a3.x += t.x; a3.y += t.y; a3.z += t.z; a3.w += t.w;
    }
    for (; j + 3 < end; j += 4) {
        uint2 u0 = H2[(size_t)srcs[j + 0] * 32 + hl];
        uint2 u1 = H2[(size_t)srcs[j + 1] * 32 + hl];
        uint2 u2 = H2[(size_t)srcs[j + 2] * 32 + hl];
        uint2 u3 = H2[(size_t)srcs[j + 3] * 32 + hl];
        float4 t;
        t = cvt4(u0); a0.x += t.x; a0.y += t.y; a0.z += t.z; a0.w += t.w;
        t = cvt4(u1); a1.x += t.x; a1.y += t.y; a1.z += t.z; a1.w += t.w;
        t = cvt4(u2); a2.x += t.x; a2.y += t.y; a2.z += t.z; a2.w += t.w;
        t = cvt4(u3); a3.x += t.x; a3.y += t.y; a3.z += t.z; a3.w += t.w;
    }
    for (; j < end; ++j) {
        float4 t = cvt4(H2[(size_t)srcs[j] * 32 + hl]);
        a0.x += t.x; a0.y += t.y; a0.z += t.z; a0.w += t.w;
    }
    a0.x += a1.x + a2.x + a3.x;
    a0.y += a1.y + a2.y + a3.y;
    a0.z += a1.z + a2.z + a3.z;
    a0.w += a1.w + a2.w + a3.w;

    float di = dinv[n];
    float4 bv = ((const float4*)bias)[hl];
    float ox = di * a0.x + bv.x;
    float oy = di * a0.y + bv.y;
    float oz = di * a0.z + bv.z;
    float ow = di * a0.w + bv.w;
    if (do_relu) {
        ox = fmaxf(ox, 0.f); oy = fmaxf(oy, 0.f);
        oz = fmaxf(oz, 0.f); ow = fmaxf(ow, 0.f);
    }
    uint2 o;
    o.x = pack2(ox, oy);
    o.y = pack2(oz, ow);
    ((uint2*)Z)[(size_t)n * 32 + hl] = o;
}

// Decode: 4 pairs per half-wave -> 8 row-gathers in flight, 4 interleaved shfl chains,
// one float4 store per group.
__global__ __launch_bounds__(256) void decode_kernel(const unsigned short* __restrict__ Z,
                                                     const int* __restrict__ pa,
                                                     const int* __restrict__ pb,
                                                     float* __restrict__ out, int P) {
    int grp = (int)((blockIdx.x * blockDim.x + threadIdx.x) >> 5);  // half-wave id
    int hl = threadIdx.x & 31;
    int p0 = grp * 4;
    if (p0 >= P) return;
    const uint2* Z2 = (const uint2*)Z;

    if (p0 + 3 < P) {
        int A0 = pa[p0], A1 = pa[p0 + 1], A2 = pa[p0 + 2], A3 = pa[p0 + 3];
        int B0 = pb[p0], B1 = pb[p0 + 1], B2 = pb[p0 + 2], B3 = pb[p0 + 3];
        uint2 ua0 = Z2[(size_t)A0 * 32 + hl];
        uint2 ub0 = Z2[(size_t)B0 * 32 + hl];
        uint2 ua1 = Z2[(size_t)A1 * 32 + hl];
        uint2 ub1 = Z2[(size_t)B1 * 32 + hl];
        uint2 ua2 = Z2[(size_t)A2 * 32 + hl];
        uint2 ub2 = Z2[(size_t)B2 * 32 + hl];
        uint2 ua3 = Z2[(size_t)A3 * 32 + hl];
        uint2 ub3 = Z2[(size_t)B3 * 32 + hl];
        float4 va, vb;
        va = cvt4(ua0); vb = cvt4(ub0);
        float v0 = va.x * vb.x + va.y * vb.y + va.z * vb.z + va.w * vb.w;
        va = cvt4(ua1); vb = cvt4(ub1);
        float v1 = va.x * vb.x + va.y * vb.y + va.z * vb.z + va.w * vb.w;
        va = cvt4(ua2); vb = cvt4(ub2);
        float v2 = va.x * vb.x + va.y * vb.y + va.z * vb.z + va.w * vb.w;
        va = cvt4(ua3); vb = cvt4(ub3);
        float v3 = va.x * vb.x + va.y * vb.y + va.z * vb.z + va.w * vb.w;
#pragma unroll
        for (int off = 16; off > 0; off >>= 1) {
            v0 += __shfl_down(v0, off, 32);
            v1 += __shfl_down(v1, off, 32);
            v2 += __shfl_down(v2, off, 32);
            v3 += __shfl_down(v3, off, 32);
        }
        if (hl == 0) *(float4*)&out[p0] = make_float4(v0, v1, v2, v3);
    } else {
        for (int p = p0; p < P; ++p) {
            float4 va = cvt4(Z2[(size_t)pa[p] * 32 + hl]);
            float4 vb = cvt4(Z2[(size_t)pb[p] * 32 + hl]);
            float v = va.x * vb.x + va.y * vb.y + va.z * vb.z + va.w * vb.w;
#pragma unroll
            for (int off = 16; off > 0; off >>= 1) v += __shfl_down(v, off, 32);
            if (hl == 0) out[p] = v;
        }
    }
}

extern "C" void kernel_launch(void* const* d_in, const int* in_sizes, int n_in,
                              void* d_out, int out_size, void* d_ws, size_t ws_size,
                              hipStream_t stream) {
    const int*   edge_index = (const int*)d_in[0];
    const int*   edge_pairs = (const int*)d_in[1];
    const float* emb        = (const float*)d_in[2];
    const float* W1         = (const float*)d_in[3];
    const float* b1         = (const float*)d_in[4];
    const float* W2         = (const float*)d_in[5];
    const float* b2         = (const float*)d_in[6];
    float* out = (float*)d_out;

    int E = in_sizes[0] / 2;
    int P = in_sizes[1] / 2;
    int N = in_sizes[2] / 128;
    int NB = (N + 63) / 64;    // buckets (782 for N=50000; must be <= 1024)

    const int* src = edge_index;
    const int* dst = edge_index + E;
    const int* pa  = edge_pairs;
    const int* pb  = edge_pairs + P;

    char* ws = (char*)d_ws;
    size_t off = 0;
    auto alloc = [&](size_t bytes) -> void* {
        void* p = ws + off;
        off = (off + bytes + 255) & ~(size_t)255;
        return p;
    };
    unsigned short* bufA = (unsigned short*)alloc((size_t)N * 128 * 2); // h' (bf16)
    unsigned short* bufB = (unsigned short*)alloc((size_t)N * 128 * 2); // z  (bf16)
    int*   srcs_sorted  = (int*)alloc((size_t)E * sizeof(int));
    unsigned int* stage = (unsigned int*)alloc((size_t)E * sizeof(unsigned int));
    int*   row_ptr      = (int*)alloc((size_t)(N + 1) * sizeof(int));
    float* dinv         = (float*)alloc((size_t)N * sizeof(float));
    int*   bhist        = (int*)alloc((size_t)CSR_G * NB * sizeof(int));
    int*   T            = (int*)alloc((size_t)NB * sizeof(int));
    int*   bucket_base  = (int*)alloc((size_t)(NB + 1) * sizeof(int));

    // CSR build: one cooperative kernel (was 5 kernels in R7/R8).
    {
        void* args[] = {(void*)&src, (void*)&dst, (void*)&bhist, (void*)&T,
                        (void*)&bucket_base, (void*)&stage, (void*)&row_ptr,
                        (void*)&dinv, (void*)&srcs_sorted,
                        (void*)&E, (void*)&N, (void*)&NB};
        hipLaunchCooperativeKernel((void*)csr_coop_kernel, dim3(CSR_G), dim3(256),
                                   args, 0, stream);
    }

    // Layer 1: h1' = dinv*(emb@W1) -> agg+b1+relu -> z1 (bufB)
    gemm_mfma_kernel<false><<<(N + 63) / 64, 256, 0, stream>>>(emb, W1, dinv, (uint2*)bufA, N);
    agg_kernel<<<(N + 7) / 8, 256, 0, stream>>>(bufA, row_ptr, srcs_sorted, dinv, b1, bufB, N, 1);

    // Layer 2: h2' = dinv*(z1@W2) -> agg+b2 -> z2 (bufB)
    gemm_mfma_kernel<true><<<(N + 63) / 64, 256, 0, stream>>>(bufB, W2, dinv, (uint2*)bufA, N);
    agg_kernel<<<(N + 7) / 8, 256, 0, stream>>>(bufA, row_ptr, srcs_sorted, dinv, b2, bufB, N, 0);

    // Decode: 4 pairs/half-wave -> 32 pairs/block
    decode_kernel<<<(P + 31) / 32, 256, 0, stream>>>(bufB, pa, pb, out, P);
}

// Round 10
// 251.064 us; speedup vs baseline: 1.9609x; 1.9609x over previous
//
#include <hip/hip_runtime.h>

// GCN link predictor. fp32 math, bf16 intermediates + bf16 MFMA GEMM.
// Pipeline: CSR build (block-hist -> bucket scans -> stage -> scatter[+row_ptr,dinv]) ->
//           [MFMA GEMM+dinv-scale -> gather-agg]x2 -> pair-dot decode.
// norm factorization: h'[i] = dinv[i]*(x@W)[i];  z[i] = dinv[i]*(h'[i] + sum_{src->i} h'[src]) + b.
// R5: MFMA GEMM. R6 FAILED: hot global atomics (190us). R7: deterministic-offset bucket CSR.
// R8: decode 4-pairs/half-wave + agg unroll-8 (248us). R9 FAILED: coop-kernel CSR -- grid.sync
// costs ~60us each on 8 non-coherent XCDs (271us for the same work); reverted to 5 kernels.
// R10: gathers quarter-wave (16-lane groups, uint4=16B/lane) -> 2x gather streams per wave.

typedef __attribute__((ext_vector_type(8))) short short8;   // 8 bf16 (A/B frag)
typedef __attribute__((ext_vector_type(4))) float floatx4;  // C/D frag

#define STAGE_G 128   // staging blocks; records/block/bucket ~ E/(G*NB) ~ 8 (32 B sub-range)

__device__ __forceinline__ unsigned short f2bf(float f) {
    union { float f; unsigned int u; } v; v.f = f;
    unsigned int u = v.u;
    u += 0x7fffu + ((u >> 16) & 1u);   // round-to-nearest-even
    return (unsigned short)(u >> 16);
}

__device__ __forceinline__ unsigned int pack2(float a, float b) {
    return (unsigned int)f2bf(a) | ((unsigned int)f2bf(b) << 16);
}

__device__ __forceinline__ float4 cvt4(unsigned int lo, unsigned int hi) {
    float4 f;
    f.x = __uint_as_float(lo << 16);
    f.y = __uint_as_float(lo & 0xffff0000u);
    f.z = __uint_as_float(hi << 16);
    f.w = __uint_as_float(hi & 0xffff0000u);
    return f;
}

// --- CSR build (R8 5-kernel pipeline) ---

__global__ __launch_bounds__(256) void block_hist_kernel(const int* __restrict__ dst,
                                                         int* __restrict__ bhist,
                                                         int E, int NB) {
    __shared__ int bh[1024];
    int t = threadIdx.x, g = blockIdx.x;
    for (int b = t; b < NB; b += 256) bh[b] = 0;
    __syncthreads();
    int chunk = (E + gridDim.x - 1) / gridDim.x;
    int lo = g * chunk, hi = min(lo + chunk, E);
    for (int i = lo + t; i < hi; i += 256) atomicAdd(&bh[dst[i] >> 6], 1);
    __syncthreads();
    for (int b = t; b < NB; b += 256) bhist[g * NB + b] = bh[b];
}

__global__ __launch_bounds__(128) void s1_scan_blocks(int* __restrict__ bhist,
                                                      int* __restrict__ T, int NB) {
    __shared__ int s[2][128];
    int b = blockIdx.x, t = threadIdx.x;
    int v = bhist[t * NB + b];
    int cur = 0;
    s[0][t] = v;
    __syncthreads();
#pragma unroll
    for (int off = 1; off < 128; off <<= 1) {
        int nxt = cur ^ 1;
        int val = s[cur][t];
        if (t >= off) val += s[cur][t - off];
        s[nxt][t] = val;
        __syncthreads();
        cur = nxt;
    }
    int inc = s[cur][t];
    bhist[t * NB + b] = inc - v;       // exclusive over blocks
    if (t == 127) T[b] = inc;
}

__global__ __launch_bounds__(256) void s2_scan_buckets(const int* __restrict__ T,
                                                       int* __restrict__ bucket_base, int NB) {
    __shared__ int sums[256];
    int t = threadIdx.x;
    int chunk = (NB + 255) >> 8;
    int lo = t * chunk, hi = min(lo + chunk, NB);
    int s = 0;
    for (int i = lo; i < hi; ++i) s += T[i];
    sums[t] = s;
    __syncthreads();
    if (t == 0) {
        int run = 0;
        for (int i = 0; i < 256; ++i) { int v = sums[i]; sums[i] = run; run += v; }
    }
    __syncthreads();
    int run = sums[t];
    for (int i = lo; i < hi; ++i) { bucket_base[i] = run; run += T[i]; }
    if (lo < NB && hi == NB) bucket_base[NB] = run;   // == E
}

__global__ __launch_bounds__(256) void stage_kernel(const int* __restrict__ src,
                                                    const int* __restrict__ dst,
                                                    const int* __restrict__ bhist,
                                                    const int* __restrict__ bucket_base,
                                                    unsigned int* __restrict__ stage,
                                                    int E, int NB) {
    __shared__ int lcur[1024];
    int t = threadIdx.x, g = blockIdx.x;
    for (int b = t; b < NB; b += 256) lcur[b] = bucket_base[b] + bhist[g * NB + b];
    __syncthreads();
    int chunk = (E + gridDim.x - 1) / gridDim.x;
    int lo = g * chunk, hi = min(lo + chunk, E);
    for (int i = lo + t; i < hi; i += 256) {
        int d = dst[i];
        int pos = atomicAdd(&lcur[d >> 6], 1);
        stage[pos] = ((unsigned int)src[i] << 6) | (unsigned int)(d & 63);
    }
}

__global__ __launch_bounds__(256) void scatter_kernel(const unsigned int* __restrict__ stage,
                                                      const int* __restrict__ bucket_base,
                                                      int* __restrict__ row_ptr,
                                                      float* __restrict__ dinv,
                                                      int* __restrict__ srcs_sorted,
                                                      int N) {
    __shared__ int cnt[64];
    __shared__ int lcur[64];
    int b = blockIdx.x, t = threadIdx.x;
    int lo = b << 6;
    int base = bucket_base[b], basen = bucket_base[b + 1];
    if (t < 64) cnt[t] = 0;
    __syncthreads();
    for (int i = base + t; i < basen; i += 256) atomicAdd(&cnt[stage[i] & 63u], 1);
    __syncthreads();
    if (t < 64) {
        int v = cnt[t];
        int inc = v;
#pragma unroll
        for (int off = 1; off < 64; off <<= 1) {
            int x = __shfl_up(inc, off, 64);
            if (t >= off) inc += x;
        }
        int exc = inc - v;
        int node = lo + t;
        if (node < N) {
            row_ptr[node] = base + exc;
            dinv[node] = rsqrtf((float)(v + 1));   // +1 self-loop
            if (node == N - 1) row_ptr[N] = base + exc + v;
        }
        lcur[t] = base + exc;
    }
    __syncthreads();
    for (int i = base + t; i < basen; i += 256) {
        unsigned int rec = stage[i];
        int pos = atomicAdd(&lcur[rec & 63u], 1);
        srcs_sorted[pos] = (int)(rec >> 6);
    }
}

// --- MFMA GEMM: H[r][c] = bf16( dinv[r] * sum_k X[r][k]*W[k][c] ), 64x128 per block ---
template <bool BF16IN>
__global__ __launch_bounds__(256) void gemm_mfma_kernel(const void* __restrict__ Xv,
                                                        const float* __restrict__ W,
                                                        const float* __restrict__ dinv,
                                                        uint2* __restrict__ H, int N) {
    __shared__ __align__(16) char smem[50176];
    short* WB = (short*)smem;            // [nt][kt][lane][j]
    short* XL = (short*)(smem + 32768);  // [row][k], row stride 136 shorts
    float* Cst = (float*)smem;           // epilogue overlap: [row][col], stride 132 floats

    const int tid = threadIdx.x;
    const int w = tid >> 6;
    const int lane = tid & 63;
    const int blk = blockIdx.x;

    {
        const float4* W4 = (const float4*)W;
#pragma unroll
        for (int i = 0; i < 16; ++i) {
            int f = tid + i * 256;
            int k = f >> 5;
            int c4 = f & 31;
            float4 wv = W4[f];
            int kt = k >> 5, q = (k >> 3) & 3, j = k & 7;
            float e[4] = {wv.x, wv.y, wv.z, wv.w};
#pragma unroll
            for (int m = 0; m < 4; ++m) {
                int c = c4 * 4 + m;
                int nt = c >> 4;
                int ln = q * 16 + (c & 15);
                WB[((nt * 4 + kt) * 64 + ln) * 8 + j] = (short)f2bf(e[m]);
            }
        }
    }
    {
#pragma unroll
        for (int i = 0; i < 8; ++i) {
            int f = tid + i * 256;
            int row = f >> 5;
            int c4 = f & 31;
            int gr = min(blk * 64 + row, N - 1);
            uint2 u;
            if constexpr (BF16IN) {
                u = ((const uint2*)Xv)[(size_t)gr * 32 + c4];
            } else {
                float4 xv = ((const float4*)Xv)[(size_t)gr * 32 + c4];
                u.x = pack2(xv.x, xv.y);
                u.y = pack2(xv.z, xv.w);
            }
            *(uint2*)&XL[row * 136 + c4 * 4] = u;
        }
    }
    __syncthreads();

    const int arow = w * 16 + (lane & 15);
    const int koff = (lane >> 4) * 8;
    short8 a[4];
#pragma unroll
    for (int kt = 0; kt < 4; ++kt)
        a[kt] = *(const short8*)&XL[arow * 136 + kt * 32 + koff];

    floatx4 acc[8];
#pragma unroll
    for (int nt = 0; nt < 8; ++nt) acc[nt] = (floatx4){0.f, 0.f, 0.f, 0.f};

#pragma unroll
    for (int kt = 0; kt < 4; ++kt) {
#pragma unroll
        for (int nt = 0; nt < 8; ++nt) {
            short8 b = *(const short8*)&WB[((nt * 4 + kt) * 64 + lane) * 8];
            acc[nt] = __builtin_amdgcn_mfma_f32_16x16x32_bf16(a[kt], b, acc[nt], 0, 0, 0);
        }
    }
    __syncthreads();

    {
        int q = lane >> 4, cn = lane & 15;
#pragma unroll
        for (int nt = 0; nt < 8; ++nt)
#pragma unroll
            for (int r = 0; r < 4; ++r)
                Cst[(w * 16 + q * 4 + r) * 132 + nt * 16 + cn] = acc[nt][r];
    }
    __syncthreads();
    {
#pragma unroll
        for (int i = 0; i < 8; ++i) {
            int f = tid + i * 256;
            int row = f >> 5;
            int c4 = f & 31;
            int gr = blk * 64 + row;
            if (gr < N) {
                float4 v = *(float4*)&Cst[row * 132 + c4 * 4];
                float di = dinv[gr];
                uint2 o;
                o.x = pack2(v.x * di, v.y * di);
                o.y = pack2(v.z * di, v.w * di);
                H[(size_t)gr * 32 + c4] = o;
            }
        }
    }
}

// Quarter-wave (16 lanes) per node; lane holds 8 cols as uint4 (16 B) -> one 256 B row per
// quarter-wave; 4 nodes per wave. fp32 accumulate, unroll-8 with 2 accumulator sets.
__global__ __launch_bounds__(256) void agg_kernel(const unsigned short* __restrict__ Hp,
                                                  const int* __restrict__ row_ptr,
                                                  const int* __restrict__ srcs,
                                                  const float* __restrict__ dinv,
                                                  const float* __restrict__ bias,
                                                  unsigned short* __restrict__ Z,
                                                  int N, int do_relu) {
    int gw = (int)((blockIdx.x * blockDim.x + threadIdx.x) >> 6);  // wave id
    int lane = threadIdx.x & 63;
    int q = lane >> 4;       // quarter 0..3
    int hl = lane & 15;
    int n = gw * 4 + q;
    if (n >= N) return;

    const uint4* H4 = (const uint4*)Hp;   // row stride 16 uint4
    uint4 us = H4[(size_t)n * 16 + hl];   // self-loop term
    float4 a0 = cvt4(us.x, us.y);
    float4 a1 = cvt4(us.z, us.w);
    float4 b0 = make_float4(0.f, 0.f, 0.f, 0.f);
    float4 b1 = make_float4(0.f, 0.f, 0.f, 0.f);

    int j = row_ptr[n], end = row_ptr[n + 1];
    for (; j + 7 < end; j += 8) {
        uint4 u0 = H4[(size_t)srcs[j + 0] * 16 + hl];
        uint4 u1 = H4[(size_t)srcs[j + 1] * 16 + hl];
        uint4 u2 = H4[(size_t)srcs[j + 2] * 16 + hl];
        uint4 u3 = H4[(size_t)srcs[j + 3] * 16 + hl];
        uint4 u4 = H4[(size_t)srcs[j + 4] * 16 + hl];
        uint4 u5 = H4[(size_t)srcs[j + 5] * 16 + hl];
        uint4 u6 = H4[(size_t)srcs[j + 6] * 16 + hl];
        uint4 u7 = H4[(size_t)srcs[j + 7] * 16 + hl];
        float4 t;
        t = cvt4(u0.x, u0.y); a0.x += t.x; a0.y += t.y; a0.z += t.z; a0.w += t.w;
        t = cvt4(u0.z, u0.w); a1.x += t.x; a1.y += t.y; a1.z += t.z; a1.w += t.w;
        t = cvt4(u1.x, u1.y); b0.x += t.x; b0.y += t.y; b0.z += t.z; b0.w += t.w;
        t = cvt4(u1.z, u1.w); b1.x += t.x; b1.y += t.y; b1.z += t.z; b1.w += t.w;
        t = cvt4(u2.x, u2.y); a0.x += t.x; a0.y += t.y; a0.z += t.z; a0.w += t.w;
        t = cvt4(u2.z, u2.w); a1.x += t.x; a1.y += t.y; a1.z += t.z; a1.w += t.w;
        t = cvt4(u3.x, u3.y); b0.x += t.x; b0.y += t.y; b0.z += t.z; b0.w += t.w;
        t = cvt4(u3.z, u3.w); b1.x += t.x; b1.y += t.y; b1.z += t.z; b1.w += t.w;
        t = cvt4(u4.x, u4.y); a0.x += t.x; a0.y += t.y; a0.z += t.z; a0.w += t.w;
        t = cvt4(u4.z, u4.w); a1.x += t.x; a1.y += t.y; a1.z += t.z; a1.w += t.w;
        t = cvt4(u5.x, u5.y); b0.x += t.x; b0.y += t.y; b0.z += t.z; b0.w += t.w;
        t = cvt4(u5.z, u5.w); b1.x += t.x; b1.y += t.y; b1.z += t.z; b1.w += t.w;
        t = cvt4(u6.x, u6.y); a0.x += t.x; a0.y += t.y; a0.z += t.z; a0.w += t.w;
        t = cvt4(u6.z, u6.w); a1.x += t.x; a1.y += t.y; a1.z += t.z; a1.w += t.w;
        t = cvt4(u7.x, u7.y); b0.x += t.x; b0.y += t.y; b0.z += t.z; b0.w += t.w;
        t = cvt4(u7.z, u7.w); b1.x += t.x; b1.y += t.y; b1.z += t.z; b1.w += t.w;
    }
    for (; j + 3 < end; j += 4) {
        uint4 u0 = H4[(size_t)srcs[j + 0] * 16 + hl];
        uint4 u1 = H4[(size_t)srcs[j + 1] * 16 + hl];
        uint4 u2 = H4[(size_t)srcs[j + 2] * 16 + hl];
        uint4 u3 = H4[(size_t)srcs[j + 3] * 16 + hl];
        float4 t;
        t = cvt4(u0.x, u0.y); a0.x += t.x; a0.y += t.y; a0.z += t.z; a0.w += t.w;
        t = cvt4(u0.z, u0.w); a1.x += t.x; a1.y += t.y; a1.z += t.z; a1.w += t.w;
        t = cvt4(u1.x, u1.y); b0.x += t.x; b0.y += t.y; b0.z += t.z; b0.w += t.w;
        t = cvt4(u1.z, u1.w); b1.x += t.x; b1.y += t.y; b1.z += t.z; b1.w += t.w;
        t = cvt4(u2.x, u2.y); a0.x += t.x; a0.y += t.y; a0.z += t.z; a0.w += t.w;
        t = cvt4(u2.z, u2.w); a1.x += t.x; a1.y += t.y; a1.z += t.z; a1.w += t.w;
        t = cvt4(u3.x, u3.y); b0.x += t.x; b0.y += t.y; b0.z += t.z; b0.w += t.w;
        t = cvt4(u3.z, u3.w); b1.x += t.x; b1.y += t.y; b1.z += t.z; b1.w += t.w;
    }
    for (; j < end; ++j) {
        uint4 u = H4[(size_t)srcs[j] * 16 + hl];
        float4 t;
        t = cvt4(u.x, u.y); a0.x += t.x; a0.y += t.y; a0.z += t.z; a0.w += t.w;
        t = cvt4(u.z, u.w); a1.x += t.x; a1.y += t.y; a1.z += t.z; a1.w += t.w;
    }
    a0.x += b0.x; a0.y += b0.y; a0.z += b0.z; a0.w += b0.w;
    a1.x += b1.x; a1.y += b1.y; a1.z += b1.z; a1.w += b1.w;

    float di = dinv[n];
    float4 bv0 = ((const float4*)bias)[2 * hl];      // cols 8*hl .. 8*hl+3
    float4 bv1 = ((const float4*)bias)[2 * hl + 1];  // cols 8*hl+4 .. 8*hl+7
    float o0 = di * a0.x + bv0.x, o1 = di * a0.y + bv0.y;
    float o2 = di * a0.z + bv0.z, o3 = di * a0.w + bv0.w;
    float o4 = di * a1.x + bv1.x, o5 = di * a1.y + bv1.y;
    float o6 = di * a1.z + bv1.z, o7 = di * a1.w + bv1.w;
    if (do_relu) {
        o0 = fmaxf(o0, 0.f); o1 = fmaxf(o1, 0.f); o2 = fmaxf(o2, 0.f); o3 = fmaxf(o3, 0.f);
        o4 = fmaxf(o4, 0.f); o5 = fmaxf(o5, 0.f); o6 = fmaxf(o6, 0.f); o7 = fmaxf(o7, 0.f);
    }
    uint4 o;
    o.x = pack2(o0, o1);
    o.y = pack2(o2, o3);
    o.z = pack2(o4, o5);
    o.w = pack2(o6, o7);
    ((uint4*)Z)[(size_t)n * 16 + hl] = o;
}

// Decode: quarter-wave per pair, 2 pairs per quarter -> 8 pairs/wave, 4 uint4 row-gathers
// in flight per quarter; shfl-reduce over width 16 (4 steps).
__global__ __launch_bounds__(256) void decode_kernel(const unsigned short* __restrict__ Z,
                                                     const int* __restrict__ pa,
                                                     const int* __restrict__ pb,
                                                     float* __restrict__ out, int P) {
    int wv = (int)((blockIdx.x * blockDim.x + threadIdx.x) >> 6);
    int lane = threadIdx.x & 63;
    int q = lane >> 4;
    int hl = lane & 15;
    int p0 = wv * 8 + q * 2;
    if (p0 >= P) return;
    const uint4* Z4 = (const uint4*)Z;

    bool two = (p0 + 1 < P);
    int A0 = pa[p0], B0 = pb[p0];
    int A1 = two ? pa[p0 + 1] : A0;
    int B1 = two ? pb[p0 + 1] : B0;
    uint4 ua0 = Z4[(size_t)A0 * 16 + hl];
    uint4 ub0 = Z4[(size_t)B0 * 16 + hl];
    uint4 ua1 = Z4[(size_t)A1 * 16 + hl];
    uint4 ub1 = Z4[(size_t)B1 * 16 + hl];

    float4 xa, xb, ya, yb;
    xa = cvt4(ua0.x, ua0.y); xb = cvt4(ub0.x, ub0.y);
    ya = cvt4(ua0.z, ua0.w); yb = cvt4(ub0.z, ub0.w);
    float v0 = xa.x * xb.x + xa.y * xb.y + xa.z * xb.z + xa.w * xb.w
             + ya.x * yb.x + ya.y * yb.y + ya.z * yb.z + ya.w * yb.w;
    xa = cvt4(ua1.x, ua1.y); xb = cvt4(ub1.x, ub1.y);
    ya = cvt4(ua1.z, ua1.w); yb = cvt4(ub1.z, ub1.w);
    float v1 = xa.x * xb.x + xa.y * xb.y + xa.z * xb.z + xa.w * xb.w
             + ya.x * yb.x + ya.y * yb.y + ya.z * yb.z + ya.w * yb.w;
#pragma unroll
    for (int off = 8; off > 0; off >>= 1) {
        v0 += __shfl_down(v0, off, 16);
        v1 += __shfl_down(v1, off, 16);
    }
    if (hl == 0) {
        out[p0] = v0;
        if (two) out[p0 + 1] = v1;
    }
}

extern "C" void kernel_launch(void* const* d_in, const int* in_sizes, int n_in,
                              void* d_out, int out_size, void* d_ws, size_t ws_size,
                              hipStream_t stream) {
    const int*   edge_index = (const int*)d_in[0];
    const int*   edge_pairs = (const int*)d_in[1];
    const float* emb        = (const float*)d_in[2];
    const float* W1         = (const float*)d_in[3];
    const float* b1         = (const float*)d_in[4];
    const float* W2         = (const float*)d_in[5];
    const float* b2         = (const float*)d_in[6];
    float* out = (float*)d_out;

    int E = in_sizes[0] / 2;
    int P = in_sizes[1] / 2;
    int N = in_sizes[2] / 128;
    int NB = (N + 63) / 64;    // buckets (782 for N=50000; must be <= 1024)

    const int* src = edge_index;
    const int* dst = edge_index + E;
    const int* pa  = edge_pairs;
    const int* pb  = edge_pairs + P;

    char* ws = (char*)d_ws;
    size_t off = 0;
    auto alloc = [&](size_t bytes) -> void* {
        void* p = ws + off;
        off = (off + bytes + 255) & ~(size_t)255;
        return p;
    };
    unsigned short* bufA = (unsigned short*)alloc((size_t)N * 128 * 2); // h' (bf16)
    unsigned short* bufB = (unsigned short*)alloc((size_t)N * 128 * 2); // z  (bf16)
    int*   srcs_sorted  = (int*)alloc((size_t)E * sizeof(int));
    unsigned int* stage = (unsigned int*)alloc((size_t)E * sizeof(unsigned int));
    int*   row_ptr      = (int*)alloc((size_t)(N + 1) * sizeof(int));
    float* dinv         = (float*)alloc((size_t)N * sizeof(float));
    int*   bhist        = (int*)alloc((size_t)STAGE_G * NB * sizeof(int));
    int*   T            = (int*)alloc((size_t)NB * sizeof(int));
    int*   bucket_base  = (int*)alloc((size_t)(NB + 1) * sizeof(int));

    // CSR build — no hot global atomics anywhere.
    block_hist_kernel<<<STAGE_G, 256, 0, stream>>>(dst, bhist, E, NB);
    s1_scan_blocks<<<NB, 128, 0, stream>>>(bhist, T, NB);
    s2_scan_buckets<<<1, 256, 0, stream>>>(T, bucket_base, NB);
    stage_kernel<<<STAGE_G, 256, 0, stream>>>(src, dst, bhist, bucket_base, stage, E, NB);
    scatter_kernel<<<NB, 256, 0, stream>>>(stage, bucket_base, row_ptr, dinv, srcs_sorted, N);

    // Layer 1: h1' = dinv*(emb@W1) -> agg+b1+relu -> z1 (bufB)
    gemm_mfma_kernel<false><<<(N + 63) / 64, 256, 0, stream>>>(emb, W1, dinv, (uint2*)bufA, N);
    agg_kernel<<<(N + 15) / 16, 256, 0, stream>>>(bufA, row_ptr, srcs_sorted, dinv, b1, bufB, N, 1);

    // Layer 2: h2' = dinv*(z1@W2) -> agg+b2 -> z2 (bufB)
    gemm_mfma_kernel<true><<<(N + 63) / 64, 256, 0, stream>>>(bufB, W2, dinv, (uint2*)bufA, N);
    agg_kernel<<<(N + 15) / 16, 256, 0, stream>>>(bufA, row_ptr, srcs_sorted, dinv, b2, bufB, N, 0);

    // Decode: 8 pairs/wave -> 32 pairs/block
    decode_kernel<<<(P + 31) / 32, 256, 0, stream>>>(bufB, pa, pb, out, P);
}